// Round 2
// baseline (569.289 us; speedup 1.0000x reference)
//
#include <hip/hip_runtime.h>

typedef __attribute__((ext_vector_type(8))) short short8;
typedef __attribute__((ext_vector_type(4))) float floatx4;

#define NB 65536   // batches
#define WES 72     // wl e-stride (elems): 64 f + 8 pad (16B rows; bank stride 36w = 4 mod 32)
#define WBS 1160   // wl b-stride (elems): 16*72 + 8 pad (16B; bank stride 580w = 4 mod 32)

static __device__ __forceinline__ ushort f2bf(float x) {
  union { float f; unsigned u; } v; v.f = x;
  unsigned r = v.u + 0x7FFFu + ((v.u >> 16) & 1u);   // round-nearest-even
  return (ushort)(r >> 16);
}

// pack 2 f32 -> one dword of 2 bf16 (lo = first)
static __device__ __forceinline__ unsigned pk2(float lo, float hi) {
  return (unsigned)f2bf(lo) | ((unsigned)f2bf(hi) << 16);
}

// Build L = [inc(32 rows); I - d*inc^T inc (16 rows)] padded to K=32 with zeros,
// and Mt[e][g][f] = M[e][f][g] (g-major transpose so MFMA A-frags are contiguous).
__global__ void sheaf_prep(const float* __restrict__ inc,
                           const float* __restrict__ M,
                           const float* __restrict__ damp,
                           ushort* __restrict__ Mt,
                           ushort* __restrict__ L) {
  const int bid = blockIdx.x, tid = threadIdx.x;
  if (bid < 32) {
    const float* Me = M + (bid << 12);
    ushort* Mte = Mt + (bid << 12);
    for (int i = tid; i < 4096; i += 256) {
      int g = i >> 6, f = i & 63;
      Mte[(g << 6) + f] = f2bf(Me[(f << 6) + g]);
    }
  } else {
    for (int i = tid; i < 1024; i += 256) {       // rows 0-31: incidence
      int e = i >> 5, col = i & 31;
      L[(e << 5) + col] = (col < 16) ? f2bf(inc[(e << 4) + col]) : (ushort)0;
    }
    float d = damp[0];
    int p = tid >> 4, q = tid & 15;               // rows 32-47: I - d*dTd (fp32 math)
    float s = 0.f;
    for (int e = 0; e < 32; ++e)
      s += inc[(e << 4) + p] * inc[(e << 4) + q];
    float a = ((p == q) ? 1.f : 0.f) - d * s;
    L[((32 + p) << 5) + q] = f2bf(a);
    L[((32 + p) << 5) + 16 + q] = (ushort)0;
  }
}

// Flipped-operand design (validated by round-1 output-0 pass): A = S^T fragment
// (m = c = b*64+f, gathered from global), B = L rows. D rows = consecutive f ->
// packed b64 wl writes + dwordx4 diffused stores. No st staging buffer; e16-31
// results stashed in VGPRs (bf16) until chunk-1 step-2.
// Bisection vs failed round 1: NO inline asm (pure f2bf), and step-2 wl reads
// use b64 uint2-pair loads (the original kernel's proven pattern) not b128.
__global__ __launch_bounds__(256, 4) void sheaf_main(
    const float* __restrict__ S,
    const ushort* __restrict__ Mt,
    const ushort* __restrict__ L,
    float* __restrict__ out) {
  __shared__ __align__(16) ushort wl[16 * WBS];   // [b][eloc][f] bf16, 37120 B
  __shared__ float h1s[4][16];

  const int tid = threadIdx.x;
  const int lane = tid & 63;
  const int w = tid >> 6;
  const int quad = lane >> 4;
  const int l15 = lane & 15;
  const int h = quad & 1;             // quads 2,3 duplicate 0,1 (k=16..31 hits L's zero pad)

  // B-fragments of L (broadcast from L2): lane n=l15 -> L row, k=quad*8+j -> p
  short8 bL0 = *(const short8*)(L + (l15) * 32 + (quad << 3));        // e 0-15
  short8 bL1 = *(const short8*)(L + (16 + l15) * 32 + (quad << 3));   // e 16-31
  short8 bLp = *(const short8*)(L + (32 + l15) * 32 + (quad << 3));   // diffusion rows

  float hp = 0.f;
  uint2 stash[16];                    // e16-31 weighted, packed bf16 (32 VGPRs)

  // ---- main loop: gather S, 3 MFMAs, wl(e0-15) write, stash(e16-31), diffused store
  #pragma unroll
  for (int t = 0; t < 16; ++t) {
    const int ctile = (w << 4) + t;
    const int b = ctile >> 2;                       // tile's batch
    const int f0 = ((t & 3) << 4) + (quad << 2);    // f base of this lane's D rows
    // A gather: lane m=l15 -> f = (t&3)*16+l15 ; k -> p = h*8+j
    const float* gp = S + ((((size_t)blockIdx.x << 4) + b) << 10)
                        + (h << 9) + ((t & 3) << 4) + l15;
    float g0 = gp[0],   g1 = gp[64],  g2 = gp[128], g3 = gp[192];
    float g4 = gp[256], g5 = gp[320], g6 = gp[384], g7 = gp[448];
    union { short8 v; unsigned u[4]; } fa;
    fa.u[0] = pk2(g0, g1); fa.u[1] = pk2(g2, g3);
    fa.u[2] = pk2(g4, g5); fa.u[3] = pk2(g6, g7);

    floatx4 a0 = {0.f, 0.f, 0.f, 0.f};
    floatx4 a1 = {0.f, 0.f, 0.f, 0.f};
    floatx4 aD = {0.f, 0.f, 0.f, 0.f};
    a0 = __builtin_amdgcn_mfma_f32_16x16x32_bf16(fa.v, bL0, a0, 0, 0, 0);
    a1 = __builtin_amdgcn_mfma_f32_16x16x32_bf16(fa.v, bL1, a1, 0, 0, 0);
    aD = __builtin_amdgcn_mfma_f32_16x16x32_bf16(fa.v, bLp, aD, 0, 0, 0);

    // wl write: D col = e = l15, rows = f0..f0+3 -> one b64
    uint2 wv; wv.x = pk2(a0[0], a0[1]); wv.y = pk2(a0[2], a0[3]);
    *(uint2*)(wl + b * WBS + l15 * WES + f0) = wv;
    // stash e16-31
    uint2 sv; sv.x = pk2(a1[0], a1[1]); sv.y = pk2(a1[2], a1[3]);
    stash[t] = sv;
    // diffused store: D col = p = l15, rows = f0..f0+3 -> one dwordx4 (fp32)
    float4 dv = make_float4(aD[0], aD[1], aD[2], aD[3]);
    *(float4*)(out + ((((size_t)blockIdx.x << 4) + b) << 10) + (l15 << 6) + f0) = dv;
  }

  // ---- step-2: coboundary norms, 4 edges per wave per chunk
  auto step2 = [&](int ec) {
    #pragma unroll
    for (int i = 0; i < 4; ++i) {
      const int eloc = (w << 2) + i;
      const ushort* MtE = Mt + (((ec << 4) + eloc) << 12);
      float ss = 0.f;
      #pragma unroll
      for (int gt = 0; gt < 4; ++gt) {
        floatx4 acc = {0.f, 0.f, 0.f, 0.f};
        #pragma unroll
        for (int ks = 0; ks < 2; ++ks) {
          // A[m=g][k=f] = Mt[e][g][f] (16B contiguous per lane)
          short8 af = *(const short8*)(MtE + (((gt << 4) + l15) << 6) + (ks << 5) + (quad << 3));
          // B[k=f][n=b] = wl[b=l15][eloc][f]  (b64-pair load, original's pattern)
          union { short8 v; uint2 u2[2]; } ub;
          const uint2* pw = (const uint2*)(wl + l15 * WBS + eloc * WES + (ks << 5) + (quad << 3));
          ub.u2[0] = pw[0]; ub.u2[1] = pw[1];
          acc = __builtin_amdgcn_mfma_f32_16x16x32_bf16(af, ub.v, acc, 0, 0, 0);
        }
        ss += acc[0]*acc[0] + acc[1]*acc[1] + acc[2]*acc[2] + acc[3]*acc[3];
      }
      ss += __shfl_xor(ss, 16);   // sum over g across quads
      ss += __shfl_xor(ss, 32);
      hp += sqrtf(ss);            // per-(b=l15, e) L2 norm
    }
  };

  __syncthreads();
  step2(0);
  __syncthreads();                // all waves done reading wl(e0-15)

  // dump stashed e16-31 into wl
  #pragma unroll
  for (int t = 0; t < 16; ++t) {
    const int b = ((w << 4) + t) >> 2;
    const int f0 = ((t & 3) << 4) + (quad << 2);
    *(uint2*)(wl + b * WBS + l15 * WES + f0) = stash[t];
  }
  __syncthreads();
  step2(1);

  if (lane < 16) h1s[w][l15] = hp;
  __syncthreads();
  if (tid < 16) {
    float tsum = (h1s[0][tid] + h1s[1][tid] + h1s[2][tid] + h1s[3][tid]) * (1.f / 32.f);
    out[(size_t)NB * 1024 + (size_t)blockIdx.x * 16 + tid] = tsum;
  }
}

extern "C" void kernel_launch(void* const* d_in, const int* in_sizes, int n_in,
                              void* d_out, int out_size, void* d_ws, size_t ws_size,
                              hipStream_t stream) {
  const float* S   = (const float*)d_in[0];   // node_sections [B,P,F] fp32
  const float* inc = (const float*)d_in[1];   // incidence [E,P] fp32
  const float* M   = (const float*)d_in[2];   // sheaf_maps [E,F,F] fp32
  const float* dmp = (const float*)d_in[3];   // damping scalar fp32
  float* out = (float*)d_out;

  ushort* Mt = (ushort*)d_ws;        // 131072 bf16 elems (256 KB)
  ushort* L  = Mt + 131072;          // 48*32 = 1536 bf16 elems

  sheaf_prep<<<33, 256, 0, stream>>>(inc, M, dmp, Mt, L);
  sheaf_main<<<NB / 16, 256, 0, stream>>>(S, Mt, L, out);
}